// Round 6
// baseline (28756.281 us; speedup 1.0000x reference)
//
#include <hip/hip_runtime.h>

#define H 1024
#define T 4096
#define G 32            // producer blocks; block b owns units [32b, 32b+32)
#define TPB 1024        // 16 waves per block, 2 adjacent units per wave
#define SOLVE_ITERS 48  // Richardson: rho ~ 0.64 -> 0.64^48 ~ 5e-10

typedef float v2f __attribute__((ext_vector_type(2)));
typedef unsigned long long u64;
typedef u64 u64x2 __attribute__((ext_vector_type(2)));

__device__ __forceinline__ float sigmoidf_(float x) { return 1.0f / (1.0f + __expf(-x)); }
__device__ __forceinline__ float tanh_fast_(float x) { return 2.0f * sigmoidf_(2.0f * x) - 1.0f; }

__device__ __forceinline__ u64 pack_(float v, unsigned salt) {
    const unsigned lo = __float_as_uint(v);
    return ((u64)(lo ^ salt) << 32) | lo;
}

// Publish adjacent units (j even): ONE 16B volatile store of two epoch-salted
// checked pairs (R3-proven transport). Poison/stale bits can never validate,
// so no flags, no fences, no init kernel.
__device__ __forceinline__ void publish2_(u64* pb, int e, int j, float va, float vb) {
    const unsigned salt = ~(unsigned)e;
    u64x2 pk;
    pk.x = pack_(va, salt);
    pk.y = pack_(vb, salt);
    *(volatile u64x2*)(pb + (size_t)(e & 1) * H + j) = pk;
}

// Consume elements j2, j2+1 of epoch e (agent-scope loads, R3-proven) with
// s_sleep backoff to keep poll pressure off the MALL. Both pairs come from
// one producer store, so they validate together.
__device__ __forceinline__ v2f poll2_(const u64* pb, int e, int j2) {
    const unsigned salt = ~(unsigned)e;
    const u64* p = pb + (size_t)(e & 1) * H + j2;
    for (;;) {
        const u64 a = __hip_atomic_load(&p[0], __ATOMIC_RELAXED, __HIP_MEMORY_SCOPE_AGENT);
        const u64 b = __hip_atomic_load(&p[1], __ATOMIC_RELAXED, __HIP_MEMORY_SCOPE_AGENT);
        if (((((unsigned)(a >> 32)) ^ (unsigned)a) == salt) &
            ((((unsigned)(b >> 32)) ^ (unsigned)b) == salt)) {
            v2f r;
            r.x = __uint_as_float((unsigned)a);
            r.y = __uint_as_float((unsigned)b);
            return r;
        }
        __builtin_amdgcn_s_sleep(1);
    }
}

// Persistent cooperative kernel, single group of 32 blocks. Phase 0: h0 via
// Richardson epochs; phase 1: 4095 GRU epochs. All-to-all consumption gives
// implicit back-pressure -> 2-deep pbuf is race-free (producer of epoch e+1
// must first consume ALL of epoch e, so nobody laps a laggard).
__global__ __launch_bounds__(TPB) void rnn_kernel(
    const float* __restrict__ u0,
    const float* __restrict__ W_hh,
    const float* __restrict__ b_ih,
    const float* __restrict__ b_hh,
    const float* __restrict__ Amat,
    const float* __restrict__ c,
    float* __restrict__ out,
    u64* __restrict__ pbuf)          // ws: 2*H u64 = 16 KB
{
    __shared__ float hlds[2][H];

    const int tid  = threadIdx.x;
    const int lane = tid & 63;
    const int w    = tid >> 6;
    const int jA   = blockIdx.x * 32 + 2 * w;   // even; wave owns jA, jA+1
    const int jB   = jA + 1;

    // ---- preload GRU weights as float2, paired with h[2*lane + 128k] ----
    v2f wA[3][8], wB[3][8];
#pragma unroll
    for (int g = 0; g < 3; ++g) {
        const float* pa = W_hh + (size_t)(g * H + jA) * H;
        const float* pb = W_hh + (size_t)(g * H + jB) * H;
#pragma unroll
        for (int k = 0; k < 8; ++k) {
            wA[g][k] = *(const v2f*)&pa[2 * lane + 128 * k];
            wB[g][k] = *(const v2f*)&pb[2 * lane + 128 * k];
        }
    }
    const float brA = b_ih[jA] + b_hh[jA],         brB = b_ih[jB] + b_hh[jB];
    const float bzA = b_ih[H + jA] + b_hh[H + jA], bzB = b_ih[H + jB] + b_hh[H + jB];
    const float binA = b_ih[2 * H + jA],           binB = b_ih[2 * H + jB];
    const float bhnA = b_hh[2 * H + jA],           bhnB = b_hh[2 * H + jB];
    const float bjA = u0[jA] - c[jA],              bjB = u0[jB] - c[jB];

    // ---- epoch 0: publish Richardson iterate 0 (h = b) ----
    if (lane == 0) publish2_(pbuf, 0, jA, bjA, bjB);

    // ---- solve epochs 1..48: h_r = b + h_{r-1} - A h_{r-1} ----
    const float* arA = Amat + (size_t)jA * H;
    const float* arB = Amat + (size_t)jB * H;
    for (int r = 1; r <= SOLVE_ITERS; ++r) {
        const int p = (r - 1) & 1;
        if (tid < 512) {
            const v2f hv = poll2_(pbuf, r - 1, 2 * tid);
            *(v2f*)&hlds[p][2 * tid] = hv;
        }
        __syncthreads();
        v2f aA = {0.f, 0.f}, aB = {0.f, 0.f};
#pragma unroll
        for (int k = 0; k < 8; ++k) {
            const v2f hv = *(const v2f*)&hlds[p][2 * lane + 128 * k];
            aA += (*(const v2f*)&arA[2 * lane + 128 * k]) * hv;
            aB += (*(const v2f*)&arB[2 * lane + 128 * k]) * hv;
        }
        float sA = aA.x + aA.y, sB = aB.x + aB.y;
#pragma unroll
        for (int m = 32; m >= 1; m >>= 1) {
            sA += __shfl_xor(sA, m, 64);
            sB += __shfl_xor(sB, m, 64);
        }
        if (lane == 0) {
            const float hA = bjA + hlds[p][jA] - sA;
            const float hB = bjB + hlds[p][jB] - sB;
            publish2_(pbuf, r, jA, hA, hB);
            if (r == SOLVE_ITERS) {                 // hs row 0 = h0
                v2f o; o.x = hA; o.y = hB;
                *(v2f*)&out[jA] = o;
            }
        }
    }

    // ---- GRU epochs: step t consumes epoch 48+t-1, publishes 48+t ----
    for (int t = 1; t < T; ++t) {
        const int e = SOLVE_ITERS + t;
        const int p = (e - 1) & 1;
        if (tid < 512) {
            const v2f hv = poll2_(pbuf, e - 1, 2 * tid);
            *(v2f*)&hlds[p][2 * tid] = hv;
        }
        __syncthreads();

        v2f aR = {0.f, 0.f}, aZ = {0.f, 0.f}, aN = {0.f, 0.f};
        v2f bR = {0.f, 0.f}, bZ = {0.f, 0.f}, bN = {0.f, 0.f};
#pragma unroll
        for (int k = 0; k < 8; ++k) {
            const v2f hv = *(const v2f*)&hlds[p][2 * lane + 128 * k];
            aR += wA[0][k] * hv; aZ += wA[1][k] * hv; aN += wA[2][k] * hv;
            bR += wB[0][k] * hv; bZ += wB[1][k] * hv; bN += wB[2][k] * hv;
        }
        float sAr = aR.x + aR.y, sAz = aZ.x + aZ.y, sAn = aN.x + aN.y;
        float sBr = bR.x + bR.y, sBz = bZ.x + bZ.y, sBn = bN.x + bN.y;
#pragma unroll
        for (int m = 32; m >= 1; m >>= 1) {
            sAr += __shfl_xor(sAr, m, 64); sAz += __shfl_xor(sAz, m, 64);
            sAn += __shfl_xor(sAn, m, 64); sBr += __shfl_xor(sBr, m, 64);
            sBz += __shfl_xor(sBz, m, 64); sBn += __shfl_xor(sBn, m, 64);
        }
        if (lane == 0) {
            const float rA = sigmoidf_(brA + sAr);
            const float zA = sigmoidf_(bzA + sAz);
            const float nA = tanh_fast_(binA + rA * (sAn + bhnA));
            const float hA = (1.f - zA) * nA + zA * hlds[p][jA];
            const float rB = sigmoidf_(brB + sBr);
            const float zB = sigmoidf_(bzB + sBz);
            const float nB = tanh_fast_(binB + rB * (sBn + bhnB));
            const float hB = (1.f - zB) * nB + zB * hlds[p][jB];
            publish2_(pbuf, e, jA, hA, hB);          // publish FIRST (visibility)
            v2f o; o.x = hA; o.y = hB;
            *(v2f*)&out[(size_t)t * H + jA] = o;
        }
    }
}

// In-place affine map out[t] <- A @ h[t] + c. Coalesced tiled GEMM: A staged
// through padded LDS (64x65, conflict-free column reads); block's own h rows
// cached in LDS so the in-place write is safe.
#define ORT 8
__global__ __launch_bounds__(256) void obs_kernel(
    const float* __restrict__ A,
    const float* __restrict__ c,
    float* __restrict__ out)
{
    __shared__ float hl[ORT][H];     // 32 KiB
    __shared__ float at[64][65];     // 16.25 KiB
    const int tid = threadIdx.x;
    const int t0  = blockIdx.x * ORT;

    for (int i = tid; i < ORT * H / 4; i += 256)
        ((float4*)&hl[0][0])[i] = ((const float4*)(out + (size_t)t0 * H))[i];
    __syncthreads();

    const int li  = tid & 63;        // output i within 64-wide tile
    const int lt2 = (tid >> 6) * 2;  // pair of t rows

    for (int it = 0; it < 16; ++it) {
        const int i0 = it * 64;
        float acc0 = c[i0 + li], acc1 = acc0;
        for (int jt = 0; jt < 16; ++jt) {
            const int j0 = jt * 64;
            __syncthreads();         // previous at tile fully consumed
            {
                const int r0 = tid >> 4, cq = (tid & 15) * 4;
                for (int rr = r0; rr < 64; rr += 16) {
                    const float4 v = *(const float4*)&A[(size_t)(i0 + rr) * H + j0 + cq];
                    at[rr][cq] = v.x; at[rr][cq + 1] = v.y;
                    at[rr][cq + 2] = v.z; at[rr][cq + 3] = v.w;
                }
            }
            __syncthreads();
#pragma unroll 16
            for (int j = 0; j < 64; ++j) {
                const float a = at[li][j];
                acc0 += a * hl[lt2][j0 + j];
                acc1 += a * hl[lt2 + 1][j0 + j];
            }
        }
        out[(size_t)(t0 + lt2) * H + i0 + li]     = acc0;
        out[(size_t)(t0 + lt2 + 1) * H + i0 + li] = acc1;
    }
}

extern "C" void kernel_launch(void* const* d_in, const int* in_sizes, int n_in,
                              void* d_out, int out_size, void* d_ws, size_t ws_size,
                              hipStream_t stream) {
    // inputs: 0 ts, 1 u0, 2 W_ih (unused: control==0), 3 W_hh, 4 b_ih,
    //         5 b_hh, 6 A, 7 c
    const float* u0   = (const float*)d_in[1];
    const float* W_hh = (const float*)d_in[3];
    const float* b_ih = (const float*)d_in[4];
    const float* b_hh = (const float*)d_in[5];
    const float* A    = (const float*)d_in[6];
    const float* c    = (const float*)d_in[7];
    float* out = (float*)d_out;
    u64* pbuf  = (u64*)d_ws;        // 16 KB used; salt check rejects 0xAA poison

    void* args[] = { (void*)&u0, (void*)&W_hh, (void*)&b_ih, (void*)&b_hh,
                     (void*)&A, (void*)&c, (void*)&out, (void*)&pbuf };
    hipLaunchCooperativeKernel((const void*)rnn_kernel, dim3(G), dim3(TPB),
                               args, 0, stream);
    hipLaunchKernelGGL(obs_kernel, dim3(T / ORT), dim3(256), 0, stream,
                       A, c, out);
}

// Round 7
// 14812.976 us; speedup vs baseline: 1.9413x; 1.9413x over previous
//
#include <hip/hip_runtime.h>

#define H 1024
#define T 4096
#define G 64            // producer blocks; block b owns units [16b, 16b+16)
#define TPB 1024        // 16 waves per block, one hidden unit per wave
#define WPB 16
#define SOLVE_ITERS 48  // Richardson: rho ~ 0.64 -> 0.64^48 ~ 5e-10

typedef float v2f __attribute__((ext_vector_type(2)));
typedef unsigned long long u64;
typedef u64 u64x2 __attribute__((ext_vector_type(2)));

__device__ __forceinline__ float sigmoidf_(float x) { return 1.0f / (1.0f + __expf(-x)); }
__device__ __forceinline__ float tanh_fast_(float x) { return 2.0f * sigmoidf_(2.0f * x) - 1.0f; }

// Publish h[j] for epoch e: 8B agent-scope atomic store (sc1 write-through ->
// visible at the MALL coherence point immediately; R3-proven). Value packed
// with epoch-salted check word: poison/stale bits can never validate.
__device__ __forceinline__ void publish_(u64* pb, int e, int j, float v) {
    const unsigned lo = __float_as_uint(v);
    const u64 pk = ((u64)(lo ^ ~(unsigned)e) << 32) | lo;
    __hip_atomic_store(&pb[(size_t)(e & 1) * H + j], pk, __ATOMIC_RELAXED,
                       __HIP_MEMORY_SCOPE_AGENT);
}

// 16B L1+L2-bypassing load (sc0 sc1): reads straight from the MALL, so it
// observes remote agent-scope stores. May tear between the two u64 halves;
// each half self-validates via the salt, so tearing just means one more spin.
__device__ __forceinline__ u64x2 load16_coh_(const u64* p) {
    u64x2 v;
    asm volatile("global_load_dwordx4 %0, %1, off sc0 sc1\n\ts_waitcnt vmcnt(0)"
                 : "=v"(v) : "v"(p) : "memory");
    return v;
}

// Consume elements j2, j2+1 of epoch e (j2 even).
__device__ __forceinline__ v2f poll2_(const u64* pb, int e, int j2) {
    const unsigned salt = ~(unsigned)e;
    const u64* p = pb + (size_t)(e & 1) * H + j2;
    for (;;) {
        const u64x2 v = load16_coh_(p);
        if (((((unsigned)(v.x >> 32)) ^ (unsigned)v.x) == salt) &&
            ((((unsigned)(v.y >> 32)) ^ (unsigned)v.y) == salt)) {
            v2f r;
            r.x = __uint_as_float((unsigned)v.x);
            r.y = __uint_as_float((unsigned)v.y);
            return r;
        }
    }
}

// Persistent cooperative kernel, single group of 64 blocks (R3 structure).
// All-to-all consumption gives implicit back-pressure -> 2-deep pbuf safe.
__global__ __launch_bounds__(TPB) void rnn_kernel(
    const float* __restrict__ u0,
    const float* __restrict__ W_hh,
    const float* __restrict__ b_ih,
    const float* __restrict__ b_hh,
    const float* __restrict__ Amat,
    const float* __restrict__ c,
    float* __restrict__ out,
    u64* __restrict__ pbuf)          // ws: 2*H u64 = 16 KB
{
    __shared__ float hlds[2][H];

    const int tid  = threadIdx.x;
    const int lane = tid & 63;
    const int wave = tid >> 6;
    const int j    = blockIdx.x * WPB + wave;   // hidden unit 0..1023

    // ---- preload weights, stride-64 k-split: w[k] pairs with h[lane+64k] ----
    float wr[16], wz[16], wn[16];
    {
        const float* pr = W_hh + (size_t)j * H;
        const float* pz = W_hh + (size_t)(H + j) * H;
        const float* pn = W_hh + (size_t)(2 * H + j) * H;
#pragma unroll
        for (int k = 0; k < 16; ++k) {
            wr[k] = pr[lane + 64 * k];
            wz[k] = pz[lane + 64 * k];
            wn[k] = pn[lane + 64 * k];
        }
    }
    const float br  = b_ih[j]         + b_hh[j];
    const float bz  = b_ih[H + j]     + b_hh[H + j];
    const float bin = b_ih[2 * H + j];
    const float bhn = b_hh[2 * H + j];
    const float bj  = u0[j] - c[j];   // rhs of A h0 = u0 - c

    // ---- epoch 0: publish Richardson iterate 0 (h = b) ----
    if (lane == 0) publish_(pbuf, 0, j, bj);

    // ---- solve epochs 1..48: h_r = b + h_{r-1} - A h_{r-1} ----
    const float* arow = Amat + (size_t)j * H;
    for (int r = 1; r <= SOLVE_ITERS; ++r) {
        const int p = (r - 1) & 1;
        if (tid < 512) {
            const v2f hv = poll2_(pbuf, r - 1, 2 * tid);
            *(v2f*)&hlds[p][2 * tid] = hv;
        }
        __syncthreads();
        float acc = 0.f;
#pragma unroll
        for (int k = 0; k < 16; ++k) acc += arow[lane + 64 * k] * hlds[p][lane + 64 * k];
#pragma unroll
        for (int m = 32; m >= 1; m >>= 1) acc += __shfl_xor(acc, m, 64);

        if (lane == 0) {
            const float hn = bj + hlds[p][j] - acc;
            publish_(pbuf, r, j, hn);
            if (r == SOLVE_ITERS) out[j] = hn;   // hs row 0 = h0
        }
    }

    // ---- GRU epochs: step t consumes epoch 48+t-1, publishes 48+t ----
    for (int t = 1; t < T; ++t) {
        const int e = SOLVE_ITERS + t;
        const int p = (e - 1) & 1;
        if (tid < 512) {
            const v2f hv = poll2_(pbuf, e - 1, 2 * tid);
            *(v2f*)&hlds[p][2 * tid] = hv;
        }
        __syncthreads();

        float hv[16];
#pragma unroll
        for (int k = 0; k < 16; ++k) hv[k] = hlds[p][lane + 64 * k];
        float ar = 0.f, az = 0.f, an = 0.f;
#pragma unroll
        for (int k = 0; k < 16; ++k) {
            ar += wr[k] * hv[k];
            az += wz[k] * hv[k];
            an += wn[k] * hv[k];
        }
#pragma unroll
        for (int m = 32; m >= 1; m >>= 1) {
            ar += __shfl_xor(ar, m, 64);
            az += __shfl_xor(az, m, 64);
            an += __shfl_xor(an, m, 64);
        }
        if (lane == 0) {
            const float r2  = sigmoidf_(br + ar);
            const float z2  = sigmoidf_(bz + az);
            const float n2  = tanh_fast_(bin + r2 * (an + bhn));
            const float hn2 = (1.f - z2) * n2 + z2 * hlds[p][j];
            publish_(pbuf, e, j, hn2);           // publish FIRST (earliest visibility)
            out[(size_t)t * H + j] = hn2;        // plain store; read post-kernel
        }
    }
}

// In-place affine map out[t] <- A @ h[t] + c. Coalesced tiled GEMM: A staged
// through padded LDS (64x65 -> conflict-free column reads); block's own h
// rows cached in LDS so the in-place write is safe.
#define ORT 8
__global__ __launch_bounds__(256) void obs_kernel(
    const float* __restrict__ A,
    const float* __restrict__ c,
    float* __restrict__ out)
{
    __shared__ float hl[ORT][H];     // 32 KiB
    __shared__ float at[64][65];     // 16.25 KiB
    const int tid = threadIdx.x;
    const int t0  = blockIdx.x * ORT;

    for (int i = tid; i < ORT * H / 4; i += 256)
        ((float4*)&hl[0][0])[i] = ((const float4*)(out + (size_t)t0 * H))[i];
    __syncthreads();

    const int li  = tid & 63;        // output i within 64-wide tile
    const int lt2 = (tid >> 6) * 2;  // pair of t rows

    for (int it = 0; it < 16; ++it) {
        const int i0 = it * 64;
        float acc0 = c[i0 + li], acc1 = acc0;
        for (int jt = 0; jt < 16; ++jt) {
            const int j0 = jt * 64;
            __syncthreads();         // previous at tile fully consumed
            {
                const int r0 = tid >> 4, cq = (tid & 15) * 4;
                for (int rr = r0; rr < 64; rr += 16) {
                    const float4 v = *(const float4*)&A[(size_t)(i0 + rr) * H + j0 + cq];
                    at[rr][cq] = v.x; at[rr][cq + 1] = v.y;
                    at[rr][cq + 2] = v.z; at[rr][cq + 3] = v.w;
                }
            }
            __syncthreads();
#pragma unroll 16
            for (int j = 0; j < 64; ++j) {
                const float a = at[li][j];
                acc0 += a * hl[lt2][j0 + j];
                acc1 += a * hl[lt2 + 1][j0 + j];
            }
        }
        out[(size_t)(t0 + lt2) * H + i0 + li]     = acc0;
        out[(size_t)(t0 + lt2 + 1) * H + i0 + li] = acc1;
    }
}

extern "C" void kernel_launch(void* const* d_in, const int* in_sizes, int n_in,
                              void* d_out, int out_size, void* d_ws, size_t ws_size,
                              hipStream_t stream) {
    // inputs: 0 ts, 1 u0, 2 W_ih (unused: control==0), 3 W_hh, 4 b_ih,
    //         5 b_hh, 6 A, 7 c
    const float* u0   = (const float*)d_in[1];
    const float* W_hh = (const float*)d_in[3];
    const float* b_ih = (const float*)d_in[4];
    const float* b_hh = (const float*)d_in[5];
    const float* A    = (const float*)d_in[6];
    const float* c    = (const float*)d_in[7];
    float* out = (float*)d_out;
    u64* pbuf  = (u64*)d_ws;        // 16 KB; salt check rejects 0xAA poison

    void* args[] = { (void*)&u0, (void*)&W_hh, (void*)&b_ih, (void*)&b_hh,
                     (void*)&A, (void*)&c, (void*)&out, (void*)&pbuf };
    hipLaunchCooperativeKernel((const void*)rnn_kernel, dim3(G), dim3(TPB),
                               args, 0, stream);
    hipLaunchKernelGGL(obs_kernel, dim3(T / ORT), dim3(256), 0, stream,
                       A, c, out);
}